// Round 4
// baseline (260.242 us; speedup 1.0000x reference)
//
#include <hip/hip_runtime.h>

// Problem constants (from reference)
#define HH 32
#define WW 32
#define NCELL 3072              // C*H*W
#define NTOK  (128*1024)        // B*S
#define CAP   128               // slots per cell (valid front, invalid back; total ~43±6.5, 13-sigma safe)
#define EPSV  1e-6f
#define NPC   16                // register-cached rows per wave-owned cell (vcnt mean 21.3, sd 4.6)

typedef float v4f __attribute__((ext_vector_type(4)));

// ws layout (ints):
//   cnt  [0 .. NCELL)          packed per-cell counter: vcnt | icnt<<16
//   list [.. +NCELL*CAP)       token ids; valid compacted to front, invalid to back

__global__ __launch_bounds__(256) void zero_kernel(int* __restrict__ cnt) {
    cnt[blockIdx.x * 256 + threadIdx.x] = 0;
}

// One global-atomic compaction pass (hist+colscan+scatter folded into one).
// 131K atomics over 3072 L2-resident counters (~43 collisions each).
__global__ __launch_bounds__(256) void build_kernel(
        const int* __restrict__ pc, const int* __restrict__ ph,
        const int* __restrict__ pw, const int* __restrict__ mask,
        int* __restrict__ cnt, int* __restrict__ list) {
    int t = blockIdx.x * 256 + threadIdx.x;
    int cell = pc[t] * (HH * WW) + ph[t] * WW + pw[t];
    int valid = (mask[t] == 0);
    int r = atomicAdd(&cnt[cell], valid ? 1 : 0x10000);
    int slot = valid ? (r & 0xFFFF) : (CAP - 1 - (r >> 16));
    if (slot >= 0 && slot < CAP) list[cell * CAP + slot] = t;
}

// ---- v3: ONE WAVE PER CELL — zero barriers, zero cross-wave reduction ----
// Per-(cell,element) stats live in the owning lane's v4f accumulator across the
// whole token loop, so the LDS partial-sum round trip and all 3 __syncthreads
// of v2 disappear. 4 independent waves (cells) per block; slist is per-wave LDS
// (same-wave RAW needs only lgkmcnt, which the compiler inserts — no barrier).
__global__ __launch_bounds__(256, 4) void cell_kernel(
        const v4f* __restrict__ patch4, const float* __restrict__ nbuf,
        const v4f* __restrict__ mean4,  const v4f* __restrict__ m24,
        const int* __restrict__ cnt_,   const int* __restrict__ list,
        v4f* __restrict__ out4) {
    __shared__ int slist[4][CAP];
    const int tid  = threadIdx.x;
    const int wave = tid >> 6;
    const int lane = tid & 63;
    const int c    = blockIdx.x * 4 + wave;        // grid = NCELL/4 = 768

    int* myl = slist[wave];
    myl[lane]      = list[c * CAP + lane];         // 2 coalesced 256B wave loads
    myl[lane + 64] = list[c * CAP + 64 + lane];

    int cw = cnt_[c];
    int vcnt = cw & 0xFFFF;
    int icnt = cw >> 16;
    if (vcnt > CAP) vcnt = CAP;
    if (icnt > CAP - vcnt) icnt = CAP - vcnt;

    // Invalid rows first: pure fire-and-forget zero stores overlap the gathers.
    for (int i = 0; i < icnt; ++i) {
        int t = myl[CAP - 1 - i];
        __builtin_nontemporal_store((v4f)0.0f, &out4[t * 64 + lane]);
    }

    const float n_new = nbuf[c] + (float)vcnt;
    const float denom = fmaxf(n_new, 1.0f);
    const v4f   m_old = mean4[c * 64 + lane];

    // Pass 1: all valid tokens of this cell, first NPC register-cached.
    // Plain (cacheable) loads: the ~24% tail re-reads then hit L2/L3.
    v4f pcache[NPC];
    v4f sq = (v4f)0.0f, ss = (v4f)0.0f;
    #pragma unroll
    for (int j = 0; j < NPC; ++j) {
        if (j < vcnt) {
            int t = myl[j];                        // wave-uniform LDS broadcast
            v4f p = patch4[t * 64 + lane];
            pcache[j] = p;
            v4f q = p - m_old;
            sq += q;
            ss += q * q;
        }
    }
    for (int i = NPC; i < vcnt; ++i) {             // tail (~24% of cells, ~1-4 rows)
        int t = myl[i];
        v4f p = patch4[t * 64 + lane];
        v4f q = p - m_old;
        sq += q;
        ss += q * q;
    }

    // Finalize per lane — no reduction needed: this lane saw every token.
    const v4f m2v = m24[c * 64 + lane];
    const v4f dm  = sq / denom;
    const v4f mn  = m_old + dm;
    v4f var = (m2v + (ss - dm * sq)) / denom;
    if (n_new < 2.0f) var = (v4f)1.0f;
    v4f inv;
    inv.x = 1.0f / (sqrtf(var.x) + EPSV);
    inv.y = 1.0f / (sqrtf(var.y) + EPSV);
    inv.z = 1.0f / (sqrtf(var.z) + EPSV);
    inv.w = 1.0f / (sqrtf(var.w) + EPSV);

    // Pass 2: normalize from the register cache.
    #pragma unroll
    for (int j = 0; j < NPC; ++j) {
        if (j < vcnt) {
            int t = myl[j];
            v4f u = (pcache[j] - mn) * inv;
            v4f o;
            o.x = fminf(fmaxf(u.x, -5.0f), 5.0f);
            o.y = fminf(fmaxf(u.y, -5.0f), 5.0f);
            o.z = fminf(fmaxf(u.z, -5.0f), 5.0f);
            o.w = fminf(fmaxf(u.w, -5.0f), 5.0f);
            __builtin_nontemporal_store(o, &out4[t * 64 + lane]);
        }
    }
    for (int i = NPC; i < vcnt; ++i) {             // tail: re-read (L2-warm)
        int t = myl[i];
        v4f p = patch4[t * 64 + lane];
        v4f u = (p - mn) * inv;
        v4f o;
        o.x = fminf(fmaxf(u.x, -5.0f), 5.0f);
        o.y = fminf(fmaxf(u.y, -5.0f), 5.0f);
        o.z = fminf(fmaxf(u.z, -5.0f), 5.0f);
        o.w = fminf(fmaxf(u.w, -5.0f), 5.0f);
        __builtin_nontemporal_store(o, &out4[t * 64 + lane]);
    }
}

extern "C" void kernel_launch(void* const* d_in, const int* in_sizes, int n_in,
                              void* d_out, int out_size, void* d_ws, size_t ws_size,
                              hipStream_t stream) {
    const float* patches = (const float*)d_in[0];
    const int*   pc      = (const int*)  d_in[1];
    const int*   ph      = (const int*)  d_in[2];
    const int*   pw      = (const int*)  d_in[3];
    const int*   mask    = (const int*)  d_in[4];
    const float* nbuf    = (const float*)d_in[5];
    const float* mean    = (const float*)d_in[6];
    const float* m2      = (const float*)d_in[7];
    float*       out     = (float*)d_out;

    int* cnt  = (int*)d_ws;
    int* list = cnt + NCELL;

    zero_kernel <<<NCELL / 256, 256, 0, stream>>>(cnt);
    build_kernel<<<NTOK / 256,  256, 0, stream>>>(pc, ph, pw, mask, cnt, list);

    cell_kernel<<<NCELL / 4, 256, 0, stream>>>(
        (const v4f*)patches, nbuf, (const v4f*)mean, (const v4f*)m2,
        cnt, list, (v4f*)out);
}